// Round 14
// baseline (686.850 us; speedup 1.0000x reference)
//
#include <hip/hip_runtime.h>
#include <math.h>

#define NNODES 10000
#define NEDGES 40000
#define DIM 64
#define WS 200      // LDS row stride (ushorts) for 192-k bf16 tiles (k_node)
// k_econv tiles: EB edges/block, grid (625, 2): K-split halves of the i-chunks
#define EB 64
#define OTS 72      // out_t stride (bf16)
#define BSS 72      // Bs stride (ush)

typedef short bf16x8 __attribute__((ext_vector_type(8)));
typedef float floatx4 __attribute__((ext_vector_type(4)));
typedef float floatx16 __attribute__((ext_vector_type(16)));

__device__ __forceinline__ float sigmoidf_(float x) { return 1.0f / (1.0f + expf(-x)); }

// float -> bf16 (RNE), returned as raw ushort
__device__ __forceinline__ unsigned short f2bf(float x) {
    unsigned int u = __float_as_uint(x);
    u += 0x7fffu + ((u >> 16) & 1u);
    return (unsigned short)(u >> 16);
}
__device__ __forceinline__ float bf2f(unsigned short h) {
    return __uint_as_float(((unsigned int)h) << 16);
}
// HW packed f32->bf16 (RNE, same rounding as f2bf): lo -> bits[15:0], hi -> bits[31:16]
__device__ __forceinline__ unsigned int cvtpk(float lo, float hi) {
    unsigned int r;
    asm("v_cvt_pk_bf16_f32 %0, %1, %2" : "=v"(r) : "v"(lo), "v"(hi));
    return r;
}
// write split [hi | hi | lo] at row base (A_cat layout for K=192 bf16 GEMM)
__device__ __forceinline__ void write_split(unsigned short* __restrict__ p, int d, float v) {
    unsigned short hi = f2bf(v);
    unsigned short lo = f2bf(v - bf2f(hi));
    p[d] = hi;
    p[64 + d] = hi;
    p[128 + d] = lo;
}

// MERGED setup kernel: 5 independent prep stages, block-range dispatch.
__global__ __launch_bounds__(256) void k_prep(const float* __restrict__ x,
                                              const float* __restrict__ lin0_w,
                                              const float* __restrict__ lin0_b,
                                              float* __restrict__ out,
                                              unsigned short* __restrict__ Abf,
                                              const float* __restrict__ em2_w,
                                              const float* __restrict__ em2_b,
                                              unsigned short* __restrict__ Bek,
                                              const float* __restrict__ root_w,
                                              const float* __restrict__ gwih,
                                              const float* __restrict__ gwhh,
                                              unsigned short* __restrict__ Wcat,
                                              const float* __restrict__ lwih,
                                              const float* __restrict__ lwhh,
                                              float* __restrict__ wcT,
                                              float* __restrict__ wrT,
                                              const int* __restrict__ ei,
                                              int* __restrict__ counts,
                                              float* __restrict__ deg) {
    const int b = blockIdx.x;
    const int tid = threadIdx.x;
    if (b < 2500) {
        int idx = b * 256 + tid;
        if (idx >= NNODES * 64) return;
        int n = idx >> 6, d = idx & 63;
        float a = lin0_b[d];
        a += x[n * 3 + 0] * lin0_w[d * 3 + 0];
        a += x[n * 3 + 1] * lin0_w[d * 3 + 1];
        a += x[n * 3 + 2] * lin0_w[d * 3 + 2];
        float v = fmaxf(a, 0.0f);
        out[idx] = v;
        write_split(Abf + (size_t)n * 192, d, v);
    } else if (b < 3540) {
        // Bek[r][k], r<4096: em2_w[r*64+k]; r>=4096 (o=r-4096): em2_b[k*64+o]
        int idx = (b - 2500) * 256 + tid;          // < 4160*64 = 266240
        if (idx >= 4160 * 64) return;
        int r = idx >> 6, k = idx & 63;
        float v = (r < 4096) ? em2_w[(size_t)r * 64 + k] : em2_b[k * 64 + (r - 4096)];
        Bek[idx] = f2bf(v);
    } else if (b < 3652) {
        int idx = (b - 3540) * 256 + tid;
        if (idx >= 448 * 64) return;
        int r = idx >> 6, i = idx & 63;
        float v;
        if (r < 64) v = root_w[i * 64 + r];
        else if (r < 256) v = gwih[(r - 64) * 64 + i];
        else v = gwhh[(r - 256) * 64 + i];
        unsigned short hi = f2bf(v);
        unsigned short lo = f2bf(v - bf2f(hi));
        unsigned short* row = Wcat + (size_t)r * 192;
        row[i] = hi;
        row[64 + i] = lo;
        row[128 + i] = hi;
    } else if (b < 3780) {
        int idx = (b - 3652) * 256 + tid;
        if (idx < 64 * 256) {
            int k = idx >> 8, t = idx & 255;
            wcT[idx] = lwih[t * 128 + k] + lwhh[t * 64 + k];
        } else if (idx < 2 * 64 * 256) {
            int i2 = idx - 64 * 256;
            int k = i2 >> 8, t = i2 & 255;
            wrT[i2] = lwih[t * 128 + 64 + k];
        }
    } else {
        int e = (b - 3780) * 256 + tid;
        if (e < NEDGES) {
            atomicAdd(&counts[ei[e]], 1);
            atomicAdd(&deg[ei[NEDGES + e]], 1.0f);
        }
    }
}

// single-block 2-phase exclusive scan; also emits cursor and invdeg
__global__ __launch_bounds__(256) void k_scan(const int* __restrict__ counts,
                                              const float* __restrict__ deg,
                                              int* __restrict__ row_start,
                                              int* __restrict__ cursor,
                                              float* __restrict__ invd) {
    __shared__ int partial[256];
    const int tid = threadIdx.x;
    const int base = tid * 40;            // 256*40 = 10240 >= NNODES
    int local[40];
    int sum = 0;
#pragma unroll
    for (int i = 0; i < 40; ++i) {
        int idx = base + i;
        int v = (idx < NNODES) ? counts[idx] : 0;
        local[i] = sum;
        sum += v;
    }
    partial[tid] = sum;
    __syncthreads();
    for (int off = 1; off < 256; off <<= 1) {
        int t = (tid >= off) ? partial[tid - off] : 0;
        __syncthreads();
        partial[tid] += t;
        __syncthreads();
    }
    const int prev = (tid > 0) ? partial[tid - 1] : 0;
#pragma unroll
    for (int i = 0; i < 40; ++i) {
        int idx = base + i;
        if (idx < NNODES) {
            int rs = prev + local[i];
            row_start[idx] = rs;
            cursor[idx] = rs;
            float dg = deg[idx];
            invd[idx] = dg > 0.0f ? 1.0f / dg : 0.0f;
        }
    }
    if (tid == 255) row_start[NNODES] = partial[255];
}

// FUSED scatter + h1: wave per edge.
__global__ __launch_bounds__(256) void k_edge(const int* __restrict__ ei,
                                              const float* __restrict__ ea,
                                              const float* __restrict__ w,
                                              const float* __restrict__ bvec,
                                              int* __restrict__ cursor,
                                              int* __restrict__ src_s,
                                              int* __restrict__ dst_s,
                                              float* __restrict__ h1s) {
    const int wv = threadIdx.x >> 6, lane = threadIdx.x & 63;
    const int e = blockIdx.x * 4 + wv;
    if (e >= NEDGES) return;
    int pos = 0;
    if (lane == 0) {
        int s = ei[e];
        pos = atomicAdd(&cursor[s], 1);
        src_s[pos] = s;
        dst_s[pos] = ei[NEDGES + e];
    }
    pos = __shfl(pos, 0);
    float a = bvec[lane];
#pragma unroll
    for (int j = 0; j < 7; ++j) a += ea[e * 7 + j] * w[lane * 7 + j];
    h1s[(size_t)pos * 64 + lane] = fmaxf(a, 0.0f);
}

// EDGE-GEMM message pass v6: R13's 32x32-MFMA structure + K-SPLIT across
// blockIdx.y (2 halves of the 64 i-chunks; half 1 also does the bias chunk).
// agg accumulation is atomicAdd (commutative, order already nondeterministic)
// so the split is correctness-trivial. Per-block serial chain halves
// (33 -> 16/17 barrier windows); queued blocks/CU 2.44 -> 4.88 with 3
// resident by LDS (46 KB) -> cross-block latency hiding.
// Wave (eh,ch) = (w&1, w>>1); A-frag: lane = edge row eh*32+(lane&31),
// k-octet (lane>>5); B-frag: lane = out col ch*32+(lane&31).
// C/D: col=lane&31, row=(reg&3)+8*(reg>>2)+4*(lane>>5)  [HW-verified m74/m101]
__global__ __launch_bounds__(256) void k_econv(const float* __restrict__ out,
                                               const float* __restrict__ h1s,
                                               const unsigned short* __restrict__ Bek,
                                               const int* __restrict__ src_s,
                                               const int* __restrict__ dst_s,
                                               float* __restrict__ agg) {
    __shared__ __align__(16) unsigned short Bs[4][64 * BSS];  // 36864 B
    __shared__ __align__(16) unsigned short out_t[EB * OTS];  // 9216 B
    const int tid = threadIdx.x;
    const int w = tid >> 6, lane = tid & 63;
    const int e0 = blockIdx.x * EB;
    const int bh = blockIdx.y;                 // K-half: 0 -> chunks 0..31, 1 -> 32..63 + bias
    // stage out[src] rows as bf16 (64 rows x 16 col4-groups = 1024 items)
#pragma unroll
    for (int j = 0; j < 4; ++j) {
        int idx = tid + 256 * j;
        int r = idx >> 4, c4 = (idx & 15) * 4;
        int s = src_s[e0 + r];
        float4 o4 = *reinterpret_cast<const float4*>(&out[(size_t)s * 64 + c4]);
        unsigned int p0 = (unsigned int)f2bf(o4.x) | ((unsigned int)f2bf(o4.y) << 16);
        unsigned int p1 = (unsigned int)f2bf(o4.z) | ((unsigned int)f2bf(o4.w) << 16);
        *reinterpret_cast<uint2*>(&out_t[r * OTS + c4]) = make_uint2(p0, p1);
    }
    const int eh = w & 1, ch = w >> 1;
    const int el = eh * 32 + (lane & 31);     // this lane's local edge row
    const int hi = lane >> 5;                  // k-octet selector
    const int ocol = ch * 32 + (lane & 31);    // this lane's output col
    // h1 -> 32 registers: hreg2[m*8+j] = h1[el, m*16 + hi*8 + j]  (m = K-window)
    float hreg2[32];
#pragma unroll
    for (int mm = 0; mm < 4; ++mm) {
        const float* hp = &h1s[(size_t)(e0 + el) * 64 + mm * 16 + hi * 8];
        float4 f0 = *reinterpret_cast<const float4*>(hp);
        float4 f1 = *reinterpret_cast<const float4*>(hp + 4);
        hreg2[mm * 8 + 0] = f0.x; hreg2[mm * 8 + 1] = f0.y;
        hreg2[mm * 8 + 2] = f0.z; hreg2[mm * 8 + 3] = f0.w;
        hreg2[mm * 8 + 4] = f1.x; hreg2[mm * 8 + 5] = f1.y;
        hreg2[mm * 8 + 6] = f1.z; hreg2[mm * 8 + 7] = f1.w;
    }
    // B chunk staging helper (8 KB: 64 rows x 64 ush)
    auto stageB = [&](int chunk, unsigned short* dst) {
#pragma unroll
        for (int j = 0; j < 2; ++j) {
            int idx = tid + 256 * j;       // 0..511
            int r = idx >> 3, c8 = (idx & 7) * 8;
            *reinterpret_cast<uint4*>(&dst[r * BSS + c8]) =
                *reinterpret_cast<const uint4*>(&Bek[(size_t)chunk * 4096 + r * 64 + c8]);
        }
    };
    floatx16 acc;
#pragma unroll
    for (int r = 0; r < 16; ++r) acc[r] = 0.0f;
    auto computeC = [&](int c, const unsigned short* bsp) {
        if (c < 64) {
            const float s = bf2f(out_t[el * OTS + c]);
#pragma unroll
            for (int mm = 0; mm < 4; ++mm) {
                union { bf16x8 v; unsigned int u[4]; } A;
#pragma unroll
                for (int j = 0; j < 4; ++j)
                    A.u[j] = cvtpk(s * hreg2[mm * 8 + 2 * j], s * hreg2[mm * 8 + 2 * j + 1]);
                bf16x8 b = *reinterpret_cast<const bf16x8*>(&bsp[ocol * BSS + mm * 16 + hi * 8]);
                acc = __builtin_amdgcn_mfma_f32_32x32x16_bf16(A.v, b, acc, 0, 0, 0);
            }
        } else {        // bias chunk: A = out-row (bf16 already)
#pragma unroll
            for (int mm = 0; mm < 4; ++mm) {
                bf16x8 a = *reinterpret_cast<const bf16x8*>(&out_t[el * OTS + mm * 16 + hi * 8]);
                bf16x8 b = *reinterpret_cast<const bf16x8*>(&bsp[ocol * BSS + mm * 16 + hi * 8]);
                acc = __builtin_amdgcn_mfma_f32_32x32x16_bf16(a, b, acc, 0, 0, 0);
            }
        }
    };
    const int c0 = bh * 32;                    // first chunk of this K-half
    const int npair = 16 + bh;                 // half 1 gets the bias window too
    // prologue: first pair of this half -> bufs 0,1
    stageB(c0 + 0, Bs[0]);
    stageB(c0 + 1, Bs[1]);
    __syncthreads();
    for (int p = 0; p < npair; ++p) {
        const int np = p + 1;
        if (np < npair) {
            const int nb = (np & 1) * 2;
            if (np < 16) {
                stageB(c0 + 2 * np, Bs[nb]);
                stageB(c0 + 2 * np + 1, Bs[nb + 1]);
            } else {
                stageB(64, Bs[nb]);            // bias window (half 1 only)
            }
        }
        const int cb = (p & 1) * 2;
        if (p < 16) {
            computeC(c0 + 2 * p, Bs[cb]);
            computeC(c0 + 2 * p + 1, Bs[cb + 1]);
        } else {
            computeC(64, Bs[cb]);
        }
        __syncthreads();
    }
    // epilogue: direct register atomics; per reg r the 64 lanes form two
    // 32-lane coalesced 128B row segments.
#pragma unroll
    for (int r = 0; r < 16; ++r) {
        int edge = e0 + eh * 32 + (r & 3) + 8 * (r >> 2) + 4 * hi;
        atomicAdd(&agg[(size_t)dst_s[edge] * 64 + ocol], acc[r]);
    }
}

// MFMA node update (32-row version): 313 blocks; B-fragments direct from
// L2-resident Wcat; LDS 34 KB; 2 barriers.
__global__ __launch_bounds__(256) void k_node(float* __restrict__ agg,
                                              const float* __restrict__ invdeg,
                                              const unsigned short* __restrict__ Wcat,
                                              const float* __restrict__ conv_b,
                                              const float* __restrict__ bih,
                                              const float* __restrict__ bhh,
                                              float* __restrict__ out,
                                              unsigned short* __restrict__ Abf) {
    __shared__ unsigned short As[32 * WS];   // out A_cat (12.8 KB)
    __shared__ unsigned short Ms[32 * WS];   // m A_cat (12.8 KB)
    __shared__ float ho[32 * 68];            // exact f32 h_old (8.7 KB)
    const int tid = threadIdx.x;
    const int row0 = blockIdx.x * 32;
#pragma unroll
    for (int j = 0; j < 3; ++j) {
        int idx = tid + 256 * j;             // 0..767 = 32 rows x 24 chunks
        int r = idx / 24, jj = idx % 24;
        int ra = row0 + r; if (ra >= NNODES) ra = NNODES - 1;
        *reinterpret_cast<uint4*>(&As[r * WS + jj * 8]) =
            *reinterpret_cast<const uint4*>(&Abf[(size_t)ra * 192 + jj * 8]);
    }
#pragma unroll
    for (int j = 0; j < 2; ++j) {
        int idx = tid + 256 * j;             // 0..511 = 32 rows x 16 float4
        int r = idx >> 4, c4 = (idx & 15) * 4;
        int ra = row0 + r; if (ra >= NNODES) ra = NNODES - 1;
        *reinterpret_cast<float4*>(&ho[r * 68 + c4]) =
            *reinterpret_cast<const float4*>(&out[(size_t)ra * 64 + c4]);
    }
    __syncthreads();
    const int wave = tid >> 6, lane = tid & 63;
    const int mi = lane & 15, q = lane >> 4;
    const int d = wave * 16 + mi;
    // phase 1: gh = out @ whh.T (Wcat rows 256+), B direct from global
    floatx4 gh[2][3];
#pragma unroll
    for (int rt = 0; rt < 2; ++rt)
#pragma unroll
        for (int g = 0; g < 3; ++g)
#pragma unroll
            for (int r = 0; r < 4; ++r) gh[rt][g][r] = 0.0f;
#pragma unroll
    for (int ks = 0; ks < 6; ++ks) {
        bf16x8 b[3];
#pragma unroll
        for (int g = 0; g < 3; ++g)
            b[g] = *reinterpret_cast<const bf16x8*>(&Wcat[(size_t)(256 + g * 64 + d) * 192 + ks * 32 + q * 8]);
#pragma unroll
        for (int rt = 0; rt < 2; ++rt) {
            bf16x8 a = *reinterpret_cast<const bf16x8*>(&As[(rt * 16 + mi) * WS + ks * 32 + q * 8]);
#pragma unroll
            for (int g = 0; g < 3; ++g)
                gh[rt][g] = __builtin_amdgcn_mfma_f32_16x16x32_bf16(a, b[g], gh[rt][g], 0, 0, 0);
        }
    }
    // phase 2: m = relu(out@root + agg*invd + conv_b) -> Ms (A_cat split); zero agg
    {
        floatx4 cm[2];
#pragma unroll
        for (int rt = 0; rt < 2; ++rt)
#pragma unroll
            for (int r = 0; r < 4; ++r) cm[rt][r] = 0.0f;
#pragma unroll
        for (int ks = 0; ks < 6; ++ks) {
            bf16x8 b = *reinterpret_cast<const bf16x8*>(&Wcat[(size_t)d * 192 + ks * 32 + q * 8]);
#pragma unroll
            for (int rt = 0; rt < 2; ++rt) {
                bf16x8 a = *reinterpret_cast<const bf16x8*>(&As[(rt * 16 + mi) * WS + ks * 32 + q * 8]);
                cm[rt] = __builtin_amdgcn_mfma_f32_16x16x32_bf16(a, b, cm[rt], 0, 0, 0);
            }
        }
        const float cb = conv_b[d];
#pragma unroll
        for (int rt = 0; rt < 2; ++rt) {
#pragma unroll
            for (int r = 0; r < 4; ++r) {
                int row = rt * 16 + q * 4 + r;
                int ra = row0 + row; int rc = (ra < NNODES) ? ra : NNODES - 1;
                float v = cm[rt][r] + agg[(size_t)rc * 64 + d] * invdeg[rc] + cb;
                if (ra < NNODES) agg[(size_t)ra * 64 + d] = 0.0f;  // ready for next iter
                v = fmaxf(v, 0.0f);
                unsigned short hi = f2bf(v);
                unsigned short lo = f2bf(v - bf2f(hi));
                Ms[row * WS + d] = hi;
                Ms[row * WS + 64 + d] = hi;
                Ms[row * WS + 128 + d] = lo;
            }
        }
    }
    __syncthreads();
    // phase 3: gi = m @ wih.T (Wcat rows 64..255) + GRU epilogue
    floatx4 gi[2][3];
#pragma unroll
    for (int rt = 0; rt < 2; ++rt)
#pragma unroll
        for (int g = 0; g < 3; ++g)
#pragma unroll
            for (int r = 0; r < 4; ++r) gi[rt][g][r] = 0.0f;
#pragma unroll
    for (int ks = 0; ks < 6; ++ks) {
        bf16x8 b[3];
#pragma unroll
        for (int g = 0; g < 3; ++g)
            b[g] = *reinterpret_cast<const bf16x8*>(&Wcat[(size_t)(64 + g * 64 + d) * 192 + ks * 32 + q * 8]);
#pragma unroll
        for (int rt = 0; rt < 2; ++rt) {
            bf16x8 a = *reinterpret_cast<const bf16x8*>(&Ms[(rt * 16 + mi) * WS + ks * 32 + q * 8]);
#pragma unroll
            for (int g = 0; g < 3; ++g)
                gi[rt][g] = __builtin_amdgcn_mfma_f32_16x16x32_bf16(a, b[g], gi[rt][g], 0, 0, 0);
        }
    }
    const float bi_r = bih[d], bi_z = bih[64 + d], bi_n = bih[128 + d];
    const float bh_r = bhh[d], bh_z = bhh[64 + d], bh_n = bhh[128 + d];
#pragma unroll
    for (int rt = 0; rt < 2; ++rt) {
#pragma unroll
        for (int r = 0; r < 4; ++r) {
            int row = rt * 16 + q * 4 + r;
            int ra = row0 + row;
            float rr = sigmoidf_(gi[rt][0][r] + bi_r + gh[rt][0][r] + bh_r);
            float zz = sigmoidf_(gi[rt][1][r] + bi_z + gh[rt][1][r] + bh_z);
            float nc = tanhf(gi[rt][2][r] + bi_n + rr * (gh[rt][2][r] + bh_n));
            float hn = (1.0f - zz) * nc + zz * ho[row * 68 + d];
            if (ra < NNODES) {
                out[(size_t)ra * 64 + d] = hn;
                write_split(Abf + (size_t)ra * 192, d, hn);
            }
        }
    }
}

// One Set2Set iteration (LSTM redundant per block + attention slice).
__global__ __launch_bounds__(256) void k_step(const float* __restrict__ out,
                                              const float* __restrict__ wcT,
                                              const float* __restrict__ wrT,
                                              const float* __restrict__ bih,
                                              const float* __restrict__ bhh,
                                              float* __restrict__ hc,   // [7][128]: hl | cl
                                              float* rs,                // [7][68]: r | S
                                              int it) {
    __shared__ float outs[256 * 65];   // 66560 B
    __shared__ float hl_s[64];
    __shared__ float qr[64];
    __shared__ float gsh[256];
    __shared__ float wsh[256];
    __shared__ float red[256];
    const int tid = threadIdx.x;
    const int n0 = blockIdx.x * 256;
#pragma unroll
    for (int j = 0; j < 16; ++j) {
        int idx = tid + 256 * j;          // 0..4095 -> (row, col4)
        int r = idx >> 4, c4 = (idx & 15) * 4;
        int n = n0 + r;
        float4 v = make_float4(0.0f, 0.0f, 0.0f, 0.0f);
        if (n < NNODES) v = *reinterpret_cast<const float4*>(&out[(size_t)n * 64 + c4]);
        outs[r * 65 + c4 + 0] = v.x;
        outs[r * 65 + c4 + 1] = v.y;
        outs[r * 65 + c4 + 2] = v.z;
        outs[r * 65 + c4 + 3] = v.w;
    }
    if (tid < 64) {
        hl_s[tid] = hc[it * 128 + tid];
        qr[tid] = (it > 0) ? rs[it * 68 + tid] / rs[it * 68 + 64] : 0.0f;
    }
    __syncthreads();
    float g0 = 0.0f, g1 = 0.0f, g2 = 0.0f, g3 = 0.0f;
#pragma unroll 4
    for (int k = 0; k < 64; k += 4) {
        g0 += hl_s[k + 0] * wcT[(k + 0) * 256 + tid] + qr[k + 0] * wrT[(k + 0) * 256 + tid];
        g1 += hl_s[k + 1] * wcT[(k + 1) * 256 + tid] + qr[k + 1] * wrT[(k + 1) * 256 + tid];
        g2 += hl_s[k + 2] * wcT[(k + 2) * 256 + tid] + qr[k + 2] * wrT[(k + 2) * 256 + tid];
        g3 += hl_s[k + 3] * wcT[(k + 3) * 256 + tid] + qr[k + 3] * wrT[(k + 3) * 256 + tid];
    }
    gsh[tid] = bih[tid] + bhh[tid] + ((g0 + g1) + (g2 + g3));
    __syncthreads();
    if (tid < 64) {
        float ig = sigmoidf_(gsh[tid]);
        float fg = sigmoidf_(gsh[64 + tid]);
        float gg = tanhf(gsh[128 + tid]);
        float og = sigmoidf_(gsh[192 + tid]);
        float c = fg * hc[it * 128 + 64 + tid] + ig * gg;
        float h = og * tanhf(c);
        hl_s[tid] = h;                       // new q for attention
        hc[(it + 1) * 128 + tid] = h;        // benign duplicate writes
        hc[(it + 1) * 128 + 64 + tid] = c;
    }
    __syncthreads();
    float w = 0.0f;
    if (n0 + tid < NNODES) {
        const float* row = &outs[tid * 65];
        float e0 = 0.0f, e1 = 0.0f, e2 = 0.0f, e3 = 0.0f;
#pragma unroll 8
        for (int k = 0; k < 64; k += 4) {
            e0 += row[k + 0] * hl_s[k + 0];
            e1 += row[k + 1] * hl_s[k + 1];
            e2 += row[k + 2] * hl_s[k + 2];
            e3 += row[k + 3] * hl_s[k + 3];
        }
        w = expf((e0 + e1) + (e2 + e3));
    }
    wsh[tid] = w;
    red[tid] = w;
    __syncthreads();
    for (int s = 128; s > 0; s >>= 1) {
        if (tid < s) red[tid] += red[tid + s];
        __syncthreads();
    }
    if (tid == 0) atomicAdd(&rs[(it + 1) * 68 + 64], red[0]);
    const int grp = tid >> 6, d = tid & 63;
    float a0 = 0.0f, a1 = 0.0f;
#pragma unroll 8
    for (int j = 0; j < 64; j += 2) {
        a0 += wsh[grp * 64 + j] * outs[(grp * 64 + j) * 65 + d];
        a1 += wsh[grp * 64 + j + 1] * outs[(grp * 64 + j + 1) * 65 + d];
    }
    atomicAdd(&rs[(it + 1) * 68 + d], a0 + a1);
}

__global__ __launch_bounds__(128) void k_out(const float* __restrict__ hc,
                                             const float* __restrict__ rs,
                                             const float* __restrict__ lin1_w,
                                             const float* __restrict__ lin1_b,
                                             const float* __restrict__ lin3_w,
                                             const float* __restrict__ lin3_b,
                                             float* __restrict__ dout) {
    __shared__ float qs[128];
    __shared__ float hs[64];
    int tid = threadIdx.x;
    qs[tid] = (tid < 64) ? hc[6 * 128 + tid] : rs[6 * 68 + (tid - 64)] / rs[6 * 68 + 64];
    __syncthreads();
    if (tid < 64) {
        float a = lin1_b[tid];
        for (int k = 0; k < 128; ++k) a += qs[k] * lin1_w[tid * 128 + k];
        hs[tid] = fmaxf(a, 0.0f);
    }
    __syncthreads();
    if (tid == 0) {
        float a = lin3_b[0];
        for (int k = 0; k < 64; ++k) a += hs[k] * lin3_w[k];
        dout[0] = a;
    }
}

extern "C" void kernel_launch(void* const* d_in, const int* in_sizes, int n_in,
                              void* d_out, int out_size, void* d_ws, size_t ws_size,
                              hipStream_t stream) {
    const float* x         = (const float*)d_in[0];
    const float* edge_attr = (const float*)d_in[1];
    const int*   ei        = (const int*)d_in[2];
    const float* lin0_w    = (const float*)d_in[4];
    const float* lin0_b    = (const float*)d_in[5];
    const float* em1_w     = (const float*)d_in[6];
    const float* em1_b     = (const float*)d_in[7];
    const float* em2_w     = (const float*)d_in[8];
    const float* em2_b     = (const float*)d_in[9];
    const float* root_w    = (const float*)d_in[10];
    const float* conv_b    = (const float*)d_in[11];
    const float* gru_wih   = (const float*)d_in[12];
    const float* gru_whh   = (const float*)d_in[13];
    const float* gru_bih   = (const float*)d_in[14];
    const float* gru_bhh   = (const float*)d_in[15];
    const float* lstm_wih  = (const float*)d_in[16];
    const float* lstm_whh  = (const float*)d_in[17];
    const float* lstm_bih  = (const float*)d_in[18];
    const float* lstm_bhh  = (const float*)d_in[19];
    const float* lin1_w    = (const float*)d_in[20];
    const float* lin1_b    = (const float*)d_in[21];
    const float* lin3_w    = (const float*)d_in[22];
    const float* lin3_b    = (const float*)d_in[23];

    float* ws = (float*)d_ws;
    size_t off = 0;
    unsigned short* Abf  = (unsigned short*)(ws + off); off += (size_t)NNODES * 192 / 2;
    unsigned short* Bek  = (unsigned short*)(ws + off); off += (size_t)4160 * 64 / 2;
    unsigned short* Wcat = (unsigned short*)(ws + off); off += (size_t)448 * 192 / 2;
    float* h1s   = ws + off; off += (size_t)NEDGES * 64;
    float* outb  = ws + off; off += (size_t)NNODES * 64;
    float* agg   = ws + off; off += (size_t)NNODES * 64;
    float* deg   = ws + off; off += NNODES;   // deg, counts, cursor contiguous (one memset)
    int*   counts    = (int*)(ws + off); off += NNODES;
    int*   cursor    = (int*)(ws + off); off += NNODES;
    int*   row_start = (int*)(ws + off); off += NNODES + 4;
    int*   src_s     = (int*)(ws + off); off += NEDGES;
    int*   dst_s     = (int*)(ws + off); off += NEDGES;
    float* invd  = ws + off; off += NNODES;
    float* wcT   = ws + off; off += 64 * 256;
    float* wrT   = ws + off; off += 64 * 256;
    float* rs    = ws + off; off += 7 * 68;     // rs + hc contiguous -> one memset
    float* hc    = ws + off; off += 7 * 128;

    hipMemsetAsync(deg, 0, 3 * NNODES * sizeof(float), stream);
    hipMemsetAsync(agg, 0, (size_t)NNODES * 64 * sizeof(float), stream);  // iter-0 agg
    hipMemsetAsync(rs, 0, (7 * 68 + 7 * 128) * sizeof(float), stream);
    k_prep<<<3937, 256, 0, stream>>>(x, lin0_w, lin0_b, outb, Abf,
                                     em2_w, em2_b, Bek,
                                     root_w, gru_wih, gru_whh, Wcat,
                                     lstm_wih, lstm_whh, wcT, wrT,
                                     ei, counts, deg);
    k_scan<<<1, 256, 0, stream>>>(counts, deg, row_start, cursor, invd);
    k_edge<<<10000, 256, 0, stream>>>(ei, edge_attr, em1_w, em1_b, cursor, src_s, dst_s, h1s);

    for (int t = 0; t < 6; ++t) {
        k_econv<<<dim3(625, 2), 256, 0, stream>>>(outb, h1s, Bek, src_s, dst_s, agg);
        k_node<<<313, 256, 0, stream>>>(agg, invd, Wcat, conv_b, gru_bih, gru_bhh,
                                        outb, Abf);
    }

    for (int it = 0; it < 6; ++it)
        k_step<<<40, 256, 0, stream>>>(outb, wcT, wrT, lstm_bih, lstm_bhh, hc, rs, it);
    k_out<<<1, 128, 0, stream>>>(hc, rs, lin1_w, lin1_b, lin3_w, lin3_b, (float*)d_out);
}

// Round 15
// 570.986 us; speedup vs baseline: 1.2029x; 1.2029x over previous
//
#include <hip/hip_runtime.h>
#include <math.h>

#define NNODES 10000
#define NEDGES 40000
#define DIM 64
#define WS 200      // LDS row stride (ushorts) for 192-k bf16 tiles (k_node)
// k_econv tiles: EB edges/block, 625 blocks (exactly 40000 edges)
#define EB 64
#define OTS 72      // out_t stride (bf16)
#define BSS 72      // Bs stride (ush)

typedef short bf16x8 __attribute__((ext_vector_type(8)));
typedef float floatx4 __attribute__((ext_vector_type(4)));
typedef float floatx16 __attribute__((ext_vector_type(16)));

__device__ __forceinline__ float sigmoidf_(float x) { return 1.0f / (1.0f + expf(-x)); }

// float -> bf16 (RNE), returned as raw ushort
__device__ __forceinline__ unsigned short f2bf(float x) {
    unsigned int u = __float_as_uint(x);
    u += 0x7fffu + ((u >> 16) & 1u);
    return (unsigned short)(u >> 16);
}
__device__ __forceinline__ float bf2f(unsigned short h) {
    return __uint_as_float(((unsigned int)h) << 16);
}
// HW packed f32->bf16 (RNE, same rounding as f2bf): lo -> bits[15:0], hi -> bits[31:16]
__device__ __forceinline__ unsigned int cvtpk(float lo, float hi) {
    unsigned int r;
    asm("v_cvt_pk_bf16_f32 %0, %1, %2" : "=v"(r) : "v"(lo), "v"(hi));
    return r;
}
// write split [hi | hi | lo] at row base (A_cat layout for K=192 bf16 GEMM)
__device__ __forceinline__ void write_split(unsigned short* __restrict__ p, int d, float v) {
    unsigned short hi = f2bf(v);
    unsigned short lo = f2bf(v - bf2f(hi));
    p[d] = hi;
    p[64 + d] = hi;
    p[128 + d] = lo;
}

// MERGED setup kernel: 5 independent prep stages, block-range dispatch.
__global__ __launch_bounds__(256) void k_prep(const float* __restrict__ x,
                                              const float* __restrict__ lin0_w,
                                              const float* __restrict__ lin0_b,
                                              float* __restrict__ out,
                                              unsigned short* __restrict__ Abf,
                                              const float* __restrict__ em2_w,
                                              const float* __restrict__ em2_b,
                                              unsigned short* __restrict__ Bek,
                                              const float* __restrict__ root_w,
                                              const float* __restrict__ gwih,
                                              const float* __restrict__ gwhh,
                                              unsigned short* __restrict__ Wcat,
                                              const float* __restrict__ lwih,
                                              const float* __restrict__ lwhh,
                                              float* __restrict__ wcT,
                                              float* __restrict__ wrT,
                                              const int* __restrict__ ei,
                                              int* __restrict__ counts,
                                              float* __restrict__ deg) {
    const int b = blockIdx.x;
    const int tid = threadIdx.x;
    if (b < 2500) {
        int idx = b * 256 + tid;
        if (idx >= NNODES * 64) return;
        int n = idx >> 6, d = idx & 63;
        float a = lin0_b[d];
        a += x[n * 3 + 0] * lin0_w[d * 3 + 0];
        a += x[n * 3 + 1] * lin0_w[d * 3 + 1];
        a += x[n * 3 + 2] * lin0_w[d * 3 + 2];
        float v = fmaxf(a, 0.0f);
        out[idx] = v;
        write_split(Abf + (size_t)n * 192, d, v);
    } else if (b < 3540) {
        // Bek[r][k], r<4096: em2_w[r*64+k]; r>=4096 (o=r-4096): em2_b[k*64+o]
        int idx = (b - 2500) * 256 + tid;          // < 4160*64 = 266240
        if (idx >= 4160 * 64) return;
        int r = idx >> 6, k = idx & 63;
        float v = (r < 4096) ? em2_w[(size_t)r * 64 + k] : em2_b[k * 64 + (r - 4096)];
        Bek[idx] = f2bf(v);
    } else if (b < 3652) {
        int idx = (b - 3540) * 256 + tid;
        if (idx >= 448 * 64) return;
        int r = idx >> 6, i = idx & 63;
        float v;
        if (r < 64) v = root_w[i * 64 + r];
        else if (r < 256) v = gwih[(r - 64) * 64 + i];
        else v = gwhh[(r - 256) * 64 + i];
        unsigned short hi = f2bf(v);
        unsigned short lo = f2bf(v - bf2f(hi));
        unsigned short* row = Wcat + (size_t)r * 192;
        row[i] = hi;
        row[64 + i] = lo;
        row[128 + i] = hi;
    } else if (b < 3780) {
        int idx = (b - 3652) * 256 + tid;
        if (idx < 64 * 256) {
            int k = idx >> 8, t = idx & 255;
            wcT[idx] = lwih[t * 128 + k] + lwhh[t * 64 + k];
        } else if (idx < 2 * 64 * 256) {
            int i2 = idx - 64 * 256;
            int k = i2 >> 8, t = i2 & 255;
            wrT[i2] = lwih[t * 128 + 64 + k];
        }
    } else {
        int e = (b - 3780) * 256 + tid;
        if (e < NEDGES) {
            atomicAdd(&counts[ei[e]], 1);
            atomicAdd(&deg[ei[NEDGES + e]], 1.0f);
        }
    }
}

// single-block 2-phase exclusive scan; also emits cursor and invdeg
__global__ __launch_bounds__(256) void k_scan(const int* __restrict__ counts,
                                              const float* __restrict__ deg,
                                              int* __restrict__ row_start,
                                              int* __restrict__ cursor,
                                              float* __restrict__ invd) {
    __shared__ int partial[256];
    const int tid = threadIdx.x;
    const int base = tid * 40;            // 256*40 = 10240 >= NNODES
    int local[40];
    int sum = 0;
#pragma unroll
    for (int i = 0; i < 40; ++i) {
        int idx = base + i;
        int v = (idx < NNODES) ? counts[idx] : 0;
        local[i] = sum;
        sum += v;
    }
    partial[tid] = sum;
    __syncthreads();
    for (int off = 1; off < 256; off <<= 1) {
        int t = (tid >= off) ? partial[tid - off] : 0;
        __syncthreads();
        partial[tid] += t;
        __syncthreads();
    }
    const int prev = (tid > 0) ? partial[tid - 1] : 0;
#pragma unroll
    for (int i = 0; i < 40; ++i) {
        int idx = base + i;
        if (idx < NNODES) {
            int rs = prev + local[i];
            row_start[idx] = rs;
            cursor[idx] = rs;
            float dg = deg[idx];
            invd[idx] = dg > 0.0f ? 1.0f / dg : 0.0f;
        }
    }
    if (tid == 255) row_start[NNODES] = partial[255];
}

// FUSED scatter + h1: wave per edge.
__global__ __launch_bounds__(256) void k_edge(const int* __restrict__ ei,
                                              const float* __restrict__ ea,
                                              const float* __restrict__ w,
                                              const float* __restrict__ bvec,
                                              int* __restrict__ cursor,
                                              int* __restrict__ src_s,
                                              int* __restrict__ dst_s,
                                              float* __restrict__ h1s) {
    const int wv = threadIdx.x >> 6, lane = threadIdx.x & 63;
    const int e = blockIdx.x * 4 + wv;
    if (e >= NEDGES) return;
    int pos = 0;
    if (lane == 0) {
        int s = ei[e];
        pos = atomicAdd(&cursor[s], 1);
        src_s[pos] = s;
        dst_s[pos] = ei[NEDGES + e];
    }
    pos = __shfl(pos, 0);
    float a = bvec[lane];
#pragma unroll
    for (int j = 0; j < 7; ++j) a += ea[e * 7 + j] * w[lane * 7 + j];
    h1s[(size_t)pos * 64 + lane] = fmaxf(a, 0.0f);
}

// EDGE-GEMM message pass (champion R13 config): mfma_f32_32x32x16_bf16, one
// wave covers 32 edges x 32 out cols -> per-chunk B LDS reads halved vs the
// 16x16 version (conflicts 5.5M -> 0.96M measured). Pair-processed chunks,
// 4 LDS buffers, register-atomic epilogue, h1 in registers. NO K-split
// (R14 showed it doubles staging/atomic traffic for a net regression).
// Wave (eh,ch) = (w&1, w>>1); A-frag: lane = edge row eh*32+(lane&31),
// k-octet (lane>>5); B-frag: lane = out col ch*32+(lane&31).
// C/D: col=lane&31, row=(reg&3)+8*(reg>>2)+4*(lane>>5)  [HW-verified m74/m101]
__global__ __launch_bounds__(256) void k_econv(const float* __restrict__ out,
                                               const float* __restrict__ h1s,
                                               const unsigned short* __restrict__ Bek,
                                               const int* __restrict__ src_s,
                                               const int* __restrict__ dst_s,
                                               float* __restrict__ agg) {
    __shared__ __align__(16) unsigned short Bs[4][64 * BSS];  // 36864 B
    __shared__ __align__(16) unsigned short out_t[EB * OTS];  // 9216 B
    const int tid = threadIdx.x;
    const int w = tid >> 6, lane = tid & 63;
    const int e0 = blockIdx.x * EB;
    // stage out[src] rows as bf16 (64 rows x 16 col4-groups = 1024 items)
#pragma unroll
    for (int j = 0; j < 4; ++j) {
        int idx = tid + 256 * j;
        int r = idx >> 4, c4 = (idx & 15) * 4;
        int s = src_s[e0 + r];
        float4 o4 = *reinterpret_cast<const float4*>(&out[(size_t)s * 64 + c4]);
        unsigned int p0 = (unsigned int)f2bf(o4.x) | ((unsigned int)f2bf(o4.y) << 16);
        unsigned int p1 = (unsigned int)f2bf(o4.z) | ((unsigned int)f2bf(o4.w) << 16);
        *reinterpret_cast<uint2*>(&out_t[r * OTS + c4]) = make_uint2(p0, p1);
    }
    const int eh = w & 1, ch = w >> 1;
    const int el = eh * 32 + (lane & 31);     // this lane's local edge row
    const int hi = lane >> 5;                  // k-octet selector
    const int ocol = ch * 32 + (lane & 31);    // this lane's output col
    // h1 -> 32 registers: hreg2[m*8+j] = h1[el, m*16 + hi*8 + j]  (m = K-window)
    float hreg2[32];
#pragma unroll
    for (int mm = 0; mm < 4; ++mm) {
        const float* hp = &h1s[(size_t)(e0 + el) * 64 + mm * 16 + hi * 8];
        float4 f0 = *reinterpret_cast<const float4*>(hp);
        float4 f1 = *reinterpret_cast<const float4*>(hp + 4);
        hreg2[mm * 8 + 0] = f0.x; hreg2[mm * 8 + 1] = f0.y;
        hreg2[mm * 8 + 2] = f0.z; hreg2[mm * 8 + 3] = f0.w;
        hreg2[mm * 8 + 4] = f1.x; hreg2[mm * 8 + 5] = f1.y;
        hreg2[mm * 8 + 6] = f1.z; hreg2[mm * 8 + 7] = f1.w;
    }
    // B chunk staging helper (8 KB: 64 rows x 64 ush)
    auto stageB = [&](int chunk, unsigned short* dst) {
#pragma unroll
        for (int j = 0; j < 2; ++j) {
            int idx = tid + 256 * j;       // 0..511
            int r = idx >> 3, c8 = (idx & 7) * 8;
            *reinterpret_cast<uint4*>(&dst[r * BSS + c8]) =
                *reinterpret_cast<const uint4*>(&Bek[(size_t)chunk * 4096 + r * 64 + c8]);
        }
    };
    floatx16 acc;
#pragma unroll
    for (int r = 0; r < 16; ++r) acc[r] = 0.0f;
    auto computeC = [&](int c, const unsigned short* bsp) {
        if (c < 64) {
            const float s = bf2f(out_t[el * OTS + c]);
#pragma unroll
            for (int mm = 0; mm < 4; ++mm) {
                union { bf16x8 v; unsigned int u[4]; } A;
#pragma unroll
                for (int j = 0; j < 4; ++j)
                    A.u[j] = cvtpk(s * hreg2[mm * 8 + 2 * j], s * hreg2[mm * 8 + 2 * j + 1]);
                bf16x8 b = *reinterpret_cast<const bf16x8*>(&bsp[ocol * BSS + mm * 16 + hi * 8]);
                acc = __builtin_amdgcn_mfma_f32_32x32x16_bf16(A.v, b, acc, 0, 0, 0);
            }
        } else {        // bias chunk: A = out-row (bf16 already)
#pragma unroll
            for (int mm = 0; mm < 4; ++mm) {
                bf16x8 a = *reinterpret_cast<const bf16x8*>(&out_t[el * OTS + mm * 16 + hi * 8]);
                bf16x8 b = *reinterpret_cast<const bf16x8*>(&bsp[ocol * BSS + mm * 16 + hi * 8]);
                acc = __builtin_amdgcn_mfma_f32_32x32x16_bf16(a, b, acc, 0, 0, 0);
            }
        }
    };
    // prologue: pair 0 (chunks 0,1) -> bufs 0,1
    stageB(0, Bs[0]);
    stageB(1, Bs[1]);
    __syncthreads();
    // 33 pairs: p<32 -> chunks {2p, 2p+1}; p==32 -> bias chunk 64
    for (int p = 0; p < 33; ++p) {
        if (p < 32) {
            const int nb = ((p + 1) & 1) * 2;
            if (p + 1 < 32) {
                stageB(2 * (p + 1), Bs[nb]);
                stageB(2 * (p + 1) + 1, Bs[nb + 1]);
            } else {
                stageB(64, Bs[nb]);          // pair 32 = bias only
            }
        }
        const int cb = (p & 1) * 2;
        if (p < 32) {
            computeC(2 * p, Bs[cb]);
            computeC(2 * p + 1, Bs[cb + 1]);
        } else {
            computeC(64, Bs[cb]);
        }
        __syncthreads();
    }
    // epilogue: direct register atomics; per reg r the 64 lanes form two
    // 32-lane coalesced 128B row segments.
#pragma unroll
    for (int r = 0; r < 16; ++r) {
        int edge = e0 + eh * 32 + (r & 3) + 8 * (r >> 2) + 4 * hi;
        atomicAdd(&agg[(size_t)dst_s[edge] * 64 + ocol], acc[r]);
    }
}

// MFMA node update (32-row version): 313 blocks; B-fragments direct from
// L2-resident Wcat; LDS 34 KB; 2 barriers.
__global__ __launch_bounds__(256) void k_node(float* __restrict__ agg,
                                              const float* __restrict__ invdeg,
                                              const unsigned short* __restrict__ Wcat,
                                              const float* __restrict__ conv_b,
                                              const float* __restrict__ bih,
                                              const float* __restrict__ bhh,
                                              float* __restrict__ out,
                                              unsigned short* __restrict__ Abf) {
    __shared__ unsigned short As[32 * WS];   // out A_cat (12.8 KB)
    __shared__ unsigned short Ms[32 * WS];   // m A_cat (12.8 KB)
    __shared__ float ho[32 * 68];            // exact f32 h_old (8.7 KB)
    const int tid = threadIdx.x;
    const int row0 = blockIdx.x * 32;
#pragma unroll
    for (int j = 0; j < 3; ++j) {
        int idx = tid + 256 * j;             // 0..767 = 32 rows x 24 chunks
        int r = idx / 24, jj = idx % 24;
        int ra = row0 + r; if (ra >= NNODES) ra = NNODES - 1;
        *reinterpret_cast<uint4*>(&As[r * WS + jj * 8]) =
            *reinterpret_cast<const uint4*>(&Abf[(size_t)ra * 192 + jj * 8]);
    }
#pragma unroll
    for (int j = 0; j < 2; ++j) {
        int idx = tid + 256 * j;             // 0..511 = 32 rows x 16 float4
        int r = idx >> 4, c4 = (idx & 15) * 4;
        int ra = row0 + r; if (ra >= NNODES) ra = NNODES - 1;
        *reinterpret_cast<float4*>(&ho[r * 68 + c4]) =
            *reinterpret_cast<const float4*>(&out[(size_t)ra * 64 + c4]);
    }
    __syncthreads();
    const int wave = tid >> 6, lane = tid & 63;
    const int mi = lane & 15, q = lane >> 4;
    const int d = wave * 16 + mi;
    // phase 1: gh = out @ whh.T (Wcat rows 256+), B direct from global
    floatx4 gh[2][3];
#pragma unroll
    for (int rt = 0; rt < 2; ++rt)
#pragma unroll
        for (int g = 0; g < 3; ++g)
#pragma unroll
            for (int r = 0; r < 4; ++r) gh[rt][g][r] = 0.0f;
#pragma unroll
    for (int ks = 0; ks < 6; ++ks) {
        bf16x8 b[3];
#pragma unroll
        for (int g = 0; g < 3; ++g)
            b[g] = *reinterpret_cast<const bf16x8*>(&Wcat[(size_t)(256 + g * 64 + d) * 192 + ks * 32 + q * 8]);
#pragma unroll
        for (int rt = 0; rt < 2; ++rt) {
            bf16x8 a = *reinterpret_cast<const bf16x8*>(&As[(rt * 16 + mi) * WS + ks * 32 + q * 8]);
#pragma unroll
            for (int g = 0; g < 3; ++g)
                gh[rt][g] = __builtin_amdgcn_mfma_f32_16x16x32_bf16(a, b[g], gh[rt][g], 0, 0, 0);
        }
    }
    // phase 2: m = relu(out@root + agg*invd + conv_b) -> Ms (A_cat split); zero agg
    {
        floatx4 cm[2];
#pragma unroll
        for (int rt = 0; rt < 2; ++rt)
#pragma unroll
            for (int r = 0; r < 4; ++r) cm[rt][r] = 0.0f;
#pragma unroll
        for (int ks = 0; ks < 6; ++ks) {
            bf16x8 b = *reinterpret_cast<const bf16x8*>(&Wcat[(size_t)d * 192 + ks * 32 + q * 8]);
#pragma unroll
            for (int rt = 0; rt < 2; ++rt) {
                bf16x8 a = *reinterpret_cast<const bf16x8*>(&As[(rt * 16 + mi) * WS + ks * 32 + q * 8]);
                cm[rt] = __builtin_amdgcn_mfma_f32_16x16x32_bf16(a, b, cm[rt], 0, 0, 0);
            }
        }
        const float cb = conv_b[d];
#pragma unroll
        for (int rt = 0; rt < 2; ++rt) {
#pragma unroll
            for (int r = 0; r < 4; ++r) {
                int row = rt * 16 + q * 4 + r;
                int ra = row0 + row; int rc = (ra < NNODES) ? ra : NNODES - 1;
                float v = cm[rt][r] + agg[(size_t)rc * 64 + d] * invdeg[rc] + cb;
                if (ra < NNODES) agg[(size_t)ra * 64 + d] = 0.0f;  // ready for next iter
                v = fmaxf(v, 0.0f);
                unsigned short hi = f2bf(v);
                unsigned short lo = f2bf(v - bf2f(hi));
                Ms[row * WS + d] = hi;
                Ms[row * WS + 64 + d] = hi;
                Ms[row * WS + 128 + d] = lo;
            }
        }
    }
    __syncthreads();
    // phase 3: gi = m @ wih.T (Wcat rows 64..255) + GRU epilogue
    floatx4 gi[2][3];
#pragma unroll
    for (int rt = 0; rt < 2; ++rt)
#pragma unroll
        for (int g = 0; g < 3; ++g)
#pragma unroll
            for (int r = 0; r < 4; ++r) gi[rt][g][r] = 0.0f;
#pragma unroll
    for (int ks = 0; ks < 6; ++ks) {
        bf16x8 b[3];
#pragma unroll
        for (int g = 0; g < 3; ++g)
            b[g] = *reinterpret_cast<const bf16x8*>(&Wcat[(size_t)(64 + g * 64 + d) * 192 + ks * 32 + q * 8]);
#pragma unroll
        for (int rt = 0; rt < 2; ++rt) {
            bf16x8 a = *reinterpret_cast<const bf16x8*>(&Ms[(rt * 16 + mi) * WS + ks * 32 + q * 8]);
#pragma unroll
            for (int g = 0; g < 3; ++g)
                gi[rt][g] = __builtin_amdgcn_mfma_f32_16x16x32_bf16(a, b[g], gi[rt][g], 0, 0, 0);
        }
    }
    const float bi_r = bih[d], bi_z = bih[64 + d], bi_n = bih[128 + d];
    const float bh_r = bhh[d], bh_z = bhh[64 + d], bh_n = bhh[128 + d];
#pragma unroll
    for (int rt = 0; rt < 2; ++rt) {
#pragma unroll
        for (int r = 0; r < 4; ++r) {
            int row = rt * 16 + q * 4 + r;
            int ra = row0 + row;
            float rr = sigmoidf_(gi[rt][0][r] + bi_r + gh[rt][0][r] + bh_r);
            float zz = sigmoidf_(gi[rt][1][r] + bi_z + gh[rt][1][r] + bh_z);
            float nc = tanhf(gi[rt][2][r] + bi_n + rr * (gh[rt][2][r] + bh_n));
            float hn = (1.0f - zz) * nc + zz * ho[row * 68 + d];
            if (ra < NNODES) {
                out[(size_t)ra * 64 + d] = hn;
                write_split(Abf + (size_t)ra * 192, d, hn);
            }
        }
    }
}

// One Set2Set iteration (LSTM redundant per block + attention slice).
__global__ __launch_bounds__(256) void k_step(const float* __restrict__ out,
                                              const float* __restrict__ wcT,
                                              const float* __restrict__ wrT,
                                              const float* __restrict__ bih,
                                              const float* __restrict__ bhh,
                                              float* __restrict__ hc,   // [7][128]: hl | cl
                                              float* rs,                // [7][68]: r | S
                                              int it) {
    __shared__ float outs[256 * 65];   // 66560 B
    __shared__ float hl_s[64];
    __shared__ float qr[64];
    __shared__ float gsh[256];
    __shared__ float wsh[256];
    __shared__ float red[256];
    const int tid = threadIdx.x;
    const int n0 = blockIdx.x * 256;
#pragma unroll
    for (int j = 0; j < 16; ++j) {
        int idx = tid + 256 * j;          // 0..4095 -> (row, col4)
        int r = idx >> 4, c4 = (idx & 15) * 4;
        int n = n0 + r;
        float4 v = make_float4(0.0f, 0.0f, 0.0f, 0.0f);
        if (n < NNODES) v = *reinterpret_cast<const float4*>(&out[(size_t)n * 64 + c4]);
        outs[r * 65 + c4 + 0] = v.x;
        outs[r * 65 + c4 + 1] = v.y;
        outs[r * 65 + c4 + 2] = v.z;
        outs[r * 65 + c4 + 3] = v.w;
    }
    if (tid < 64) {
        hl_s[tid] = hc[it * 128 + tid];
        qr[tid] = (it > 0) ? rs[it * 68 + tid] / rs[it * 68 + 64] : 0.0f;
    }
    __syncthreads();
    float g0 = 0.0f, g1 = 0.0f, g2 = 0.0f, g3 = 0.0f;
#pragma unroll 4
    for (int k = 0; k < 64; k += 4) {
        g0 += hl_s[k + 0] * wcT[(k + 0) * 256 + tid] + qr[k + 0] * wrT[(k + 0) * 256 + tid];
        g1 += hl_s[k + 1] * wcT[(k + 1) * 256 + tid] + qr[k + 1] * wrT[(k + 1) * 256 + tid];
        g2 += hl_s[k + 2] * wcT[(k + 2) * 256 + tid] + qr[k + 2] * wrT[(k + 2) * 256 + tid];
        g3 += hl_s[k + 3] * wcT[(k + 3) * 256 + tid] + qr[k + 3] * wrT[(k + 3) * 256 + tid];
    }
    gsh[tid] = bih[tid] + bhh[tid] + ((g0 + g1) + (g2 + g3));
    __syncthreads();
    if (tid < 64) {
        float ig = sigmoidf_(gsh[tid]);
        float fg = sigmoidf_(gsh[64 + tid]);
        float gg = tanhf(gsh[128 + tid]);
        float og = sigmoidf_(gsh[192 + tid]);
        float c = fg * hc[it * 128 + 64 + tid] + ig * gg;
        float h = og * tanhf(c);
        hl_s[tid] = h;                       // new q for attention
        hc[(it + 1) * 128 + tid] = h;        // benign duplicate writes
        hc[(it + 1) * 128 + 64 + tid] = c;
    }
    __syncthreads();
    float w = 0.0f;
    if (n0 + tid < NNODES) {
        const float* row = &outs[tid * 65];
        float e0 = 0.0f, e1 = 0.0f, e2 = 0.0f, e3 = 0.0f;
#pragma unroll 8
        for (int k = 0; k < 64; k += 4) {
            e0 += row[k + 0] * hl_s[k + 0];
            e1 += row[k + 1] * hl_s[k + 1];
            e2 += row[k + 2] * hl_s[k + 2];
            e3 += row[k + 3] * hl_s[k + 3];
        }
        w = expf((e0 + e1) + (e2 + e3));
    }
    wsh[tid] = w;
    red[tid] = w;
    __syncthreads();
    for (int s = 128; s > 0; s >>= 1) {
        if (tid < s) red[tid] += red[tid + s];
        __syncthreads();
    }
    if (tid == 0) atomicAdd(&rs[(it + 1) * 68 + 64], red[0]);
    const int grp = tid >> 6, d = tid & 63;
    float a0 = 0.0f, a1 = 0.0f;
#pragma unroll 8
    for (int j = 0; j < 64; j += 2) {
        a0 += wsh[grp * 64 + j] * outs[(grp * 64 + j) * 65 + d];
        a1 += wsh[grp * 64 + j + 1] * outs[(grp * 64 + j + 1) * 65 + d];
    }
    atomicAdd(&rs[(it + 1) * 68 + d], a0 + a1);
}

__global__ __launch_bounds__(128) void k_out(const float* __restrict__ hc,
                                             const float* __restrict__ rs,
                                             const float* __restrict__ lin1_w,
                                             const float* __restrict__ lin1_b,
                                             const float* __restrict__ lin3_w,
                                             const float* __restrict__ lin3_b,
                                             float* __restrict__ dout) {
    __shared__ float qs[128];
    __shared__ float hs[64];
    int tid = threadIdx.x;
    qs[tid] = (tid < 64) ? hc[6 * 128 + tid] : rs[6 * 68 + (tid - 64)] / rs[6 * 68 + 64];
    __syncthreads();
    if (tid < 64) {
        float a = lin1_b[tid];
        for (int k = 0; k < 128; ++k) a += qs[k] * lin1_w[tid * 128 + k];
        hs[tid] = fmaxf(a, 0.0f);
    }
    __syncthreads();
    if (tid == 0) {
        float a = lin3_b[0];
        for (int k = 0; k < 64; ++k) a += hs[k] * lin3_w[k];
        dout[0] = a;
    }
}

extern "C" void kernel_launch(void* const* d_in, const int* in_sizes, int n_in,
                              void* d_out, int out_size, void* d_ws, size_t ws_size,
                              hipStream_t stream) {
    const float* x         = (const float*)d_in[0];
    const float* edge_attr = (const float*)d_in[1];
    const int*   ei        = (const int*)d_in[2];
    const float* lin0_w    = (const float*)d_in[4];
    const float* lin0_b    = (const float*)d_in[5];
    const float* em1_w     = (const float*)d_in[6];
    const float* em1_b     = (const float*)d_in[7];
    const float* em2_w     = (const float*)d_in[8];
    const float* em2_b     = (const float*)d_in[9];
    const float* root_w    = (const float*)d_in[10];
    const float* conv_b    = (const float*)d_in[11];
    const float* gru_wih   = (const float*)d_in[12];
    const float* gru_whh   = (const float*)d_in[13];
    const float* gru_bih   = (const float*)d_in[14];
    const float* gru_bhh   = (const float*)d_in[15];
    const float* lstm_wih  = (const float*)d_in[16];
    const float* lstm_whh  = (const float*)d_in[17];
    const float* lstm_bih  = (const float*)d_in[18];
    const float* lstm_bhh  = (const float*)d_in[19];
    const float* lin1_w    = (const float*)d_in[20];
    const float* lin1_b    = (const float*)d_in[21];
    const float* lin3_w    = (const float*)d_in[22];
    const float* lin3_b    = (const float*)d_in[23];

    float* ws = (float*)d_ws;
    size_t off = 0;
    unsigned short* Abf  = (unsigned short*)(ws + off); off += (size_t)NNODES * 192 / 2;
    unsigned short* Bek  = (unsigned short*)(ws + off); off += (size_t)4160 * 64 / 2;
    unsigned short* Wcat = (unsigned short*)(ws + off); off += (size_t)448 * 192 / 2;
    float* h1s   = ws + off; off += (size_t)NEDGES * 64;
    float* outb  = ws + off; off += (size_t)NNODES * 64;
    float* agg   = ws + off; off += (size_t)NNODES * 64;
    float* deg   = ws + off; off += NNODES;   // deg, counts, cursor contiguous (one memset)
    int*   counts    = (int*)(ws + off); off += NNODES;
    int*   cursor    = (int*)(ws + off); off += NNODES;
    int*   row_start = (int*)(ws + off); off += NNODES + 4;
    int*   src_s     = (int*)(ws + off); off += NEDGES;
    int*   dst_s     = (int*)(ws + off); off += NEDGES;
    float* invd  = ws + off; off += NNODES;
    float* wcT   = ws + off; off += 64 * 256;
    float* wrT   = ws + off; off += 64 * 256;
    float* rs    = ws + off; off += 7 * 68;     // rs + hc contiguous -> one memset
    float* hc    = ws + off; off += 7 * 128;

    hipMemsetAsync(deg, 0, 3 * NNODES * sizeof(float), stream);
    hipMemsetAsync(agg, 0, (size_t)NNODES * 64 * sizeof(float), stream);  // iter-0 agg
    hipMemsetAsync(rs, 0, (7 * 68 + 7 * 128) * sizeof(float), stream);
    k_prep<<<3937, 256, 0, stream>>>(x, lin0_w, lin0_b, outb, Abf,
                                     em2_w, em2_b, Bek,
                                     root_w, gru_wih, gru_whh, Wcat,
                                     lstm_wih, lstm_whh, wcT, wrT,
                                     ei, counts, deg);
    k_scan<<<1, 256, 0, stream>>>(counts, deg, row_start, cursor, invd);
    k_edge<<<10000, 256, 0, stream>>>(ei, edge_attr, em1_w, em1_b, cursor, src_s, dst_s, h1s);

    const int neb = NEDGES / EB;   // 625
    for (int t = 0; t < 6; ++t) {
        k_econv<<<neb, 256, 0, stream>>>(outb, h1s, Bek, src_s, dst_s, agg);
        k_node<<<313, 256, 0, stream>>>(agg, invd, Wcat, conv_b, gru_bih, gru_bhh,
                                        outb, Abf);
    }

    for (int it = 0; it < 6; ++it)
        k_step<<<40, 256, 0, stream>>>(outb, wcT, wrT, lstm_bih, lstm_bhh, hc, rs, it);
    k_out<<<1, 128, 0, stream>>>(hc, rs, lin1_w, lin1_b, lin3_w, lin3_b, (float*)d_out);
}